// Round 6
// baseline (61.223 us; speedup 1.0000x reference)
//
#include <hip/hip_runtime.h>
#include <hip/hip_bf16.h>

// Problem constants: B=32, T=256, N=1024 -> R = 8192 rows, K = N-1 = 1023 (padded to 1024)
// alpha = 0.5, b[m] = sqrt(m+1)-sqrt(m) = 1/(sqrt(m+1)+sqrt(m)), coef = sqrt(1023)/Gamma(1.5)
#define COEF 36.090511f
#define INV_COUNT (1.0f / 8388608.0f)   // 1 / (32*256*1024)

typedef __attribute__((ext_vector_type(4))) float f32x4;
typedef __attribute__((ext_vector_type(8))) __bf16 bf16x8;

typedef const __attribute__((address_space(1))) unsigned int* gas_ptr;
typedef __attribute__((address_space(3))) unsigned int* las_ptr;

__device__ __forceinline__ void load_lds16(const void* g, void* l) {
  __builtin_amdgcn_global_load_lds((gas_ptr)g, (las_ptr)l, 16, 0, 0);
}

// prep blocks 0..8191: du (bf16, padded col 1023 = 0) + per-row partials.
// blocks 8192..8263: build Mtf = Toeplitz B in MFMA-fragment order (triangular chunks only).
//   chunk c = cb*(cb+1)+kb (72 chunks, 16 KB each); elem E in chunk:
//   ksub=E>>12, wn=(E>>11)&1, fn=(E>>9)&3, lane=(E>>3)&63, kk=E&7
//   col = cb*128+wn*64+fn*16+(lane&15), k = kb*64+ksub*32+(lane>>4)*8+kk, val = b[col-k] (0 if <0)
__global__ void prep(const float* __restrict__ up, const float* __restrict__ utr,
                     __hip_bfloat16* __restrict__ du, __hip_bfloat16* __restrict__ Mtf,
                     float* __restrict__ dpart, float* __restrict__ ppart) {
  const int t = threadIdx.x;      // 256 threads
  if (blockIdx.x >= 8192) {
    const int c = blockIdx.x - 8192;    // 0..71
    int cb = 0;
    while ((cb + 1) * (cb + 2) <= c) cb++;
    const int kb = c - cb * (cb + 1);
    __hip_bfloat16* chunk = Mtf + (size_t)c * 8192;
    const int col0 = cb * 128, k0 = kb * 64;
#pragma unroll
    for (int s = 0; s < 8; s++) {
      union { ushort4 u4; __hip_bfloat16 h[4]; } pk;
#pragma unroll
      for (int e2 = 0; e2 < 4; e2++) {
        const int E = t * 32 + s * 4 + e2;
        const int ksub = E >> 12, wn = (E >> 11) & 1, fn = (E >> 9) & 3;
        const int ln = (E >> 3) & 63, kk = E & 7;
        const int col = col0 + wn * 64 + fn * 16 + (ln & 15);
        const int k = k0 + ksub * 32 + (ln >> 4) * 8 + kk;
        const int m = col - k;
        float v = 0.f;
        if (m >= 0) { float fm_ = (float)m; v = 1.0f / (sqrtf(fm_ + 1.f) + sqrtf(fm_)); }
        pk.h[e2] = __float2bfloat16(v);
      }
      *(ushort4*)(chunk + t * 32 + s * 4) = pk.u4;
    }
    return;
  }

  const int r = blockIdx.x;       // 8192 rows
  const int j0 = t * 4;
  const float* rowp = up + (size_t)r * 1024;

  f32x4 a = *(const f32x4*)(rowp + j0);
  float a4 = (t < 255) ? rowp[j0 + 4] : 0.f;
  f32x4 b = *(const f32x4*)(utr + (size_t)r * 1024 + j0);

  float d0 = a[1] - a[0];
  float d1 = a[2] - a[1];
  float d2 = a[3] - a[2];
  float d3 = (t < 255) ? (a4 - a[3]) : 0.f;   // du[1023] = 0 pad

  union { ushort4 u4; __hip_bfloat16 h[4]; } pk;
  pk.h[0] = __float2bfloat16(d0);
  pk.h[1] = __float2bfloat16(d1);
  pk.h[2] = __float2bfloat16(d2);
  pk.h[3] = __float2bfloat16(d3);
  *(ushort4*)(du + (size_t)r * 1024 + j0) = pk.u4;

  float e0 = a[0] - b[0], e1 = a[1] - b[1], e2 = a[2] - b[2], e3 = a[3] - b[3];
  float dsum = e0 * e0 + e1 * e1 + e2 * e2 + e3 * e3;

#pragma unroll
  for (int off = 32; off > 0; off >>= 1) dsum += __shfl_down(dsum, off, 64);
  __shared__ float ws4[4];
  const int lane = t & 63, w = t >> 6;
  if (lane == 0) ws4[w] = dsum;
  __syncthreads();
  if (t == 0) {
    dpart[r] = ws4[0] + ws4[1] + ws4[2] + ws4[3];
    ppart[r] = d0 * d0;   // physics residual at n=0: u_t = du[r,0], frac_lap[0] = 0
  }
}

// Y[r,i] = sum_j du[r,j] * b[i-j]; fused epilogue: resid = u_t - COEF*Y, accumulate resid^2.
// 128x128 tile, BK=64, 4 waves (2x2), A double-buffered in LDS (XOR-swizzled quads),
// B loaded DIRECTLY from fragment-ordered global Mtf (coalesced dwordx4, L1/L2-resident).
// LDS traffic/block-iter: 48 KB (was 96 KB) -> under the MFMA roof. One sync per iter.
__launch_bounds__(256, 2)
__global__ void gemm(const __hip_bfloat16* __restrict__ du,
                     const __hip_bfloat16* __restrict__ Mtf,
                     float* __restrict__ gpart) {
  __shared__ __hip_bfloat16 sA[2][8192];   // [128][64], quad-swizzled
  __shared__ float wsum[4];

  const int t = threadIdx.x;
  const int w = t >> 6;
  const int lane = t & 63;

  // XCD-aware map (bid%8 -> XCD): each XCD owns 8 rb panels x all cb; cb folded so
  // bid and bid+256 (same CU) have complementary triangular work.
  const int bid = blockIdx.x;      // 0..511
  const int xcd = bid & 7;
  const int local = bid >> 3;      // 0..63
  const int rb = xcd * 8 + (local & 7);
  const int q = local >> 3;
  const int cb = (q < 4) ? q : 11 - q;    // {0,1,2,3,7,6,5,4}
  const int row0 = rb * 128;
  const int col0 = cb * 128;
  const int nkb = 2 * (cb + 1);    // K-blocks of 64 (triangular skip)

  const f32x4 vzero = {0.f, 0.f, 0.f, 0.f};
  f32x4 acc[4][4];
#pragma unroll
  for (int i = 0; i < 4; i++)
#pragma unroll
    for (int j = 0; j < 4; j++) acc[i][j] = vzero;

  // A staging: thread t covers (row = t>>3, phys quad = t&7); source quad = phys ^ (row&7)
  const int srow = t >> 3;                       // 0..31
  const int scol = ((t & 7) ^ (srow & 7)) * 8;   // pre-swizzled source col (elements)
  const __hip_bfloat16* gA0 = du + (size_t)(row0 + srow) * 1024 + scol;

  auto stage = [&](int buf, int kb) {
    const int kc = kb * 64;
#pragma unroll
    for (int l = 0; l < 4; l++)
      load_lds16(gA0 + (size_t)l * 32 * 1024 + kc, (void*)&sA[buf][l * 2048 + t * 8]);
  };

  const int wm = w >> 1, wn = w & 1;
  const int frow = lane & 15;
  const int g4 = lane >> 4;              // logical k-quad 0..3
  // Mtf base for (cb, wn, lane); per (kb,ksub,fn): + kb*8192 + ksub*4096 + fn*512
  const __hip_bfloat16* mtf0 = Mtf + (size_t)cb * (cb + 1) * 8192 + (size_t)wn * 2048 + (size_t)lane * 8;

  auto compute = [&](int buf, int kb) {
#pragma unroll
    for (int ksub = 0; ksub < 2; ksub++) {
      const int lq = g4 | (ksub << 2);       // logical quad
      const int ph = lq ^ (frow & 7);        // physical quad (swizzle)
      bf16x8 aF[4];
#pragma unroll
      for (int fm = 0; fm < 4; fm++)
        aF[fm] = *(const bf16x8*)&sA[buf][(wm * 64 + fm * 16 + frow) * 64 + ph * 8];
#pragma unroll
      for (int fn = 0; fn < 4; fn++) {
        bf16x8 bF = *(const bf16x8*)(mtf0 + (size_t)kb * 8192 + ksub * 4096 + fn * 512);
#pragma unroll
        for (int fm = 0; fm < 4; fm++)
          acc[fm][fn] = __builtin_amdgcn_mfma_f32_16x16x32_bf16(aF[fm], bF, acc[fm][fn], 0, 0, 0);
      }
    }
  };

  stage(0, 0);
  for (int kb = 0; kb < nkb; kb++) {
    __syncthreads();                       // stage(kb) resident; buf (kb+1)&1 free
    if (kb + 1 < nkb) stage((kb + 1) & 1, kb + 1);
    compute(kb & 1, kb);
  }

  // fused epilogue: C/D layout col = lane&15, row = (lane>>4)*4 + reg  [HW-verified]
  float psum = 0.f;
  const int rbase = row0 + wm * 64 + (lane >> 4) * 4;
  const int ibase = col0 + wn * 64 + frow;
#pragma unroll
  for (int fm = 0; fm < 4; fm++) {
#pragma unroll
    for (int fn = 0; fn < 4; fn++) {
      const int icol = ibase + fn * 16;        // du index i; output position n = i+1
      if (icol < 1023) {
#pragma unroll
        for (int reg = 0; reg < 4; reg++) {
          const int r = rbase + fm * 16 + reg;
          float frac = COEF * acc[fm][fn][reg];
          float dui = __bfloat162float(du[(size_t)r * 1024 + icol]);
          float ut;
          if (icol == 1022) {
            ut = dui;                           // n = N-1 edge: u_t = du[N-2]
          } else {
            float dui1 = __bfloat162float(du[(size_t)r * 1024 + icol + 1]);
            ut = 0.5f * (dui + dui1);           // central difference
          }
          float res = ut - frac;
          psum += res * res;
        }
      }
    }
  }

#pragma unroll
  for (int off = 32; off > 0; off >>= 1) psum += __shfl_down(psum, off, 64);
  if (lane == 0) wsum[w] = psum;
  __syncthreads();
  if (t == 0) gpart[bid] = wsum[0] + wsum[1] + wsum[2] + wsum[3];
}

// Single-block tree reduction of all partials -> 3 outputs.
__global__ void finalize(const float* __restrict__ dpart, const float* __restrict__ ppart,
                         const float* __restrict__ gpart, float* __restrict__ out) {
  const int t = threadIdx.x;    // 256 threads
  float ds = 0.f, ps = 0.f;
  for (int i = t; i < 8192; i += 256) { ds += dpart[i]; ps += ppart[i]; }
  for (int i = t; i < 512; i += 256) ps += gpart[i];

#pragma unroll
  for (int off = 32; off > 0; off >>= 1) {
    ds += __shfl_down(ds, off, 64);
    ps += __shfl_down(ps, off, 64);
  }
  __shared__ float sd[4], sp[4];
  const int lane = t & 63, w = t >> 6;
  if (lane == 0) { sd[w] = ds; sp[w] = ps; }
  __syncthreads();
  if (t == 0) {
    float data = (sd[0] + sd[1] + sd[2] + sd[3]) * INV_COUNT;
    float phys = (sp[0] + sp[1] + sp[2] + sp[3]) * INV_COUNT;
    out[0] = data + 0.1f * phys;
    out[1] = data;
    out[2] = phys;
  }
}

extern "C" void kernel_launch(void* const* d_in, const int* in_sizes, int n_in,
                              void* d_out, int out_size, void* d_ws, size_t ws_size,
                              hipStream_t stream) {
  const float* u_pred = (const float*)d_in[0];
  const float* u_true = (const float*)d_in[1];
  float* out = (float*)d_out;

  char* ws = (char*)d_ws;
  float* dpart = (float*)ws;                                    // 8192 floats (32 KiB)
  float* ppart = (float*)(ws + 32768);                          // 8192 floats (32 KiB)
  float* gpart = (float*)(ws + 65536);                          // 512 floats (2 KiB)
  __hip_bfloat16* Mtf = (__hip_bfloat16*)(ws + 131072);         // 72 chunks * 16 KiB = 1.125 MiB
  __hip_bfloat16* du = (__hip_bfloat16*)(ws + 131072 + 2097152);// 8192*1024*2 = 16 MiB

  prep<<<8264, 256, 0, stream>>>(u_pred, u_true, du, Mtf, dpart, ppart);
  gemm<<<512, 256, 0, stream>>>(du, Mtf, gpart);
  finalize<<<1, 256, 0, stream>>>(dpart, ppart, gpart, out);
}

// Round 7
// 50.010 us; speedup vs baseline: 1.2242x; 1.2242x over previous
//
#include <hip/hip_runtime.h>
#include <hip/hip_bf16.h>

// Problem constants: B=32, T=256, N=1024 -> R = 8192 rows, K = N-1 = 1023 (padded to 1024)
// alpha = 0.5, b[m] = sqrt(m+1)-sqrt(m) = 1/(sqrt(m+1)+sqrt(m)), coef = sqrt(1023)/Gamma(1.5)
#define COEF 36.090511f
#define INV_COUNT (1.0f / 8388608.0f)   // 1 / (32*256*1024)

typedef __attribute__((ext_vector_type(4))) float f32x4;
typedef __attribute__((ext_vector_type(8))) __bf16 bf16x8;

typedef const __attribute__((address_space(1))) unsigned int* gas_ptr;
typedef __attribute__((address_space(3))) unsigned int* las_ptr;

__device__ __forceinline__ void load_lds16(const void* g, void* l) {
  __builtin_amdgcn_global_load_lds((gas_ptr)g, (las_ptr)l, 16, 0, 0);
}

// prep blocks 0..8191: du (bf16, padded col 1023 = 0) + per-row partials.
// blocks 8192..9215: build Mt[i][j] = b[i-j] (transposed Toeplitz), one row each.
__global__ void prep(const float* __restrict__ up, const float* __restrict__ utr,
                     __hip_bfloat16* __restrict__ du, __hip_bfloat16* __restrict__ Mt,
                     float* __restrict__ dpart, float* __restrict__ ppart) {
  const int t = threadIdx.x;      // 256 threads
  if (blockIdx.x >= 8192) {
    const int i = blockIdx.x - 8192;    // Mt row 0..1023
    const int j0 = t * 4;
    union { ushort4 u4; __hip_bfloat16 h[4]; } pk;
#pragma unroll
    for (int e = 0; e < 4; e++) {
      int m = i - (j0 + e);
      float v = 0.f;
      if (m >= 0) { float fm_ = (float)m; v = 1.0f / (sqrtf(fm_ + 1.f) + sqrtf(fm_)); }
      pk.h[e] = __float2bfloat16(v);
    }
    *(ushort4*)(Mt + (size_t)i * 1024 + j0) = pk.u4;
    return;
  }

  const int r = blockIdx.x;       // 8192 rows
  const int j0 = t * 4;
  const float* rowp = up + (size_t)r * 1024;

  f32x4 a = *(const f32x4*)(rowp + j0);
  float a4 = (t < 255) ? rowp[j0 + 4] : 0.f;
  f32x4 b = *(const f32x4*)(utr + (size_t)r * 1024 + j0);

  float d0 = a[1] - a[0];
  float d1 = a[2] - a[1];
  float d2 = a[3] - a[2];
  float d3 = (t < 255) ? (a4 - a[3]) : 0.f;   // du[1023] = 0 pad

  union { ushort4 u4; __hip_bfloat16 h[4]; } pk;
  pk.h[0] = __float2bfloat16(d0);
  pk.h[1] = __float2bfloat16(d1);
  pk.h[2] = __float2bfloat16(d2);
  pk.h[3] = __float2bfloat16(d3);
  *(ushort4*)(du + (size_t)r * 1024 + j0) = pk.u4;

  float e0 = a[0] - b[0], e1 = a[1] - b[1], e2 = a[2] - b[2], e3 = a[3] - b[3];
  float dsum = e0 * e0 + e1 * e1 + e2 * e2 + e3 * e3;

#pragma unroll
  for (int off = 32; off > 0; off >>= 1) dsum += __shfl_down(dsum, off, 64);
  __shared__ float ws4[4];
  const int lane = t & 63, w = t >> 6;
  if (lane == 0) ws4[w] = dsum;
  __syncthreads();
  if (t == 0) {
    dpart[r] = ws4[0] + ws4[1] + ws4[2] + ws4[3];
    ppart[r] = d0 * d0;   // physics residual at n=0: u_t = du[r,0], frac_lap[0] = 0
  }
}

// Y[r,i] = sum_j du[r,j] * b[i-j]; fused epilogue: resid = u_t - COEF*Y, accumulate resid^2.
// 128x128 tile, BK=64, 4 waves, double-buffered LDS, XOR-swizzled quads, counted vmcnt.
// Block map: XCD-aware (bid%8 -> XCD, each XCD owns 8 rb panels = 2MB du slice) AND
// dispatch-order-robust triangular balance: cb chosen so BOTH pairings
// (local 2k,2k+1 -> same CU) and (local k,k+32 -> same CU) give 18 kb-iters/CU.
__launch_bounds__(256, 2)
__global__ void gemm(const __hip_bfloat16* __restrict__ du,
                     const __hip_bfloat16* __restrict__ Mt,
                     float* __restrict__ gpart) {
  __shared__ __hip_bfloat16 sA[2][8192];   // [128][64], quad-swizzled
  __shared__ __hip_bfloat16 sB[2][8192];
  __shared__ float wsum[4];

  const int t = threadIdx.x;
  const int w = t >> 6;
  const int lane = t & 63;

  const int bid = blockIdx.x;      // 0..511
  const int xcd = bid & 7;
  const int local = bid >> 3;      // 0..63
  const int e = local & 1;
  const int j = local >> 1;        // 0..31
  const int h = (j < 16) ? (j & 7) : 7 - (j & 7);
  const int cb = e ? 7 - h : h;                 // pairs (2k,2k+1) and (k,k+32) both sum to 7
  const int rb = xcd * 8 + (((j >> 3) << 1) | e);   // bijective with cb per XCD
  const int row0 = rb * 128;
  const int col0 = cb * 128;
  const int nkb = 2 * (cb + 1);    // K-blocks of 64 (triangular skip)

  const f32x4 vzero = {0.f, 0.f, 0.f, 0.f};
  f32x4 acc[4][4];
#pragma unroll
  for (int i = 0; i < 4; i++)
#pragma unroll
    for (int jj = 0; jj < 4; jj++) acc[i][jj] = vzero;

  // staging: thread t covers (row = t>>3, phys quad = t&7); source quad = phys ^ (row&7)
  const int srow = t >> 3;                       // 0..31
  const int scol = ((t & 7) ^ (srow & 7)) * 8;   // pre-swizzled source col (elements)
  const __hip_bfloat16* gA0 = du + (size_t)(row0 + srow) * 1024 + scol;
  const __hip_bfloat16* gB0 = Mt + (size_t)(col0 + srow) * 1024 + scol;

  auto stage = [&](int buf, int kb) {
    const int kc = kb * 64;
#pragma unroll
    for (int l = 0; l < 4; l++)
      load_lds16(gA0 + (size_t)l * 32 * 1024 + kc, (void*)&sA[buf][l * 2048 + t * 8]);
#pragma unroll
    for (int l = 0; l < 4; l++)
      load_lds16(gB0 + (size_t)l * 32 * 1024 + kc, (void*)&sB[buf][l * 2048 + t * 8]);
  };

  const int wm = w >> 1, wn = w & 1;
  const int frow = lane & 15;
  const int g4 = lane >> 4;              // logical k-quad 0..3
  const int ph0 = g4 ^ (frow & 7);       // ksub=0 physical quad

  auto compute = [&](int buf) {
#pragma unroll
    for (int ksub = 0; ksub < 2; ksub++) {
      const int ph = ph0 ^ (ksub << 2);  // ksub=1 -> logical quad +4
      bf16x8 aF[4], bF[4];
#pragma unroll
      for (int fm = 0; fm < 4; fm++)
        aF[fm] = *(const bf16x8*)&sA[buf][(wm * 64 + fm * 16 + frow) * 64 + ph * 8];
#pragma unroll
      for (int fn = 0; fn < 4; fn++)
        bF[fn] = *(const bf16x8*)&sB[buf][(wn * 64 + fn * 16 + frow) * 64 + ph * 8];
#pragma unroll
      for (int fm = 0; fm < 4; fm++)
#pragma unroll
        for (int fn = 0; fn < 4; fn++)
          acc[fm][fn] = __builtin_amdgcn_mfma_f32_16x16x32_bf16(aF[fm], bF[fn], acc[fm][fn], 0, 0, 0);
    }
  };

  stage(0, 0);
  for (int kb = 0; kb < nkb; kb++) {
    // BARRIER A: all waves done computing kb-1 (done reading buf kb+1&1) -> safe to overwrite
    asm volatile("" ::: "memory");
    __builtin_amdgcn_s_barrier();
    asm volatile("" ::: "memory");
    if (kb + 1 < nkb) {
      stage((kb + 1) & 1, kb + 1);                    // 8 loads in flight across barrier
      asm volatile("s_waitcnt vmcnt(8)" ::: "memory"); // cur tile's 8 (from kb-1) complete
    } else {
      asm volatile("s_waitcnt vmcnt(0)" ::: "memory"); // last tile: drain
    }
    // BARRIER B: every wave's cur loads complete
    __builtin_amdgcn_s_barrier();
    asm volatile("" ::: "memory");
    compute(kb & 1);
  }

  // fused epilogue: C/D layout col = lane&15, row = (lane>>4)*4 + reg  [HW-verified]
  float psum = 0.f;
  const int rbase = row0 + wm * 64 + (lane >> 4) * 4;
  const int ibase = col0 + wn * 64 + frow;
#pragma unroll
  for (int fm = 0; fm < 4; fm++) {
#pragma unroll
    for (int fn = 0; fn < 4; fn++) {
      const int icol = ibase + fn * 16;        // du index i; output position n = i+1
      if (icol < 1023) {
#pragma unroll
        for (int reg = 0; reg < 4; reg++) {
          const int r = rbase + fm * 16 + reg;
          float frac = COEF * acc[fm][fn][reg];
          float dui = __bfloat162float(du[(size_t)r * 1024 + icol]);
          float ut;
          if (icol == 1022) {
            ut = dui;                           // n = N-1 edge: u_t = du[N-2]
          } else {
            float dui1 = __bfloat162float(du[(size_t)r * 1024 + icol + 1]);
            ut = 0.5f * (dui + dui1);           // central difference
          }
          float res = ut - frac;
          psum += res * res;
        }
      }
    }
  }

#pragma unroll
  for (int off = 32; off > 0; off >>= 1) psum += __shfl_down(psum, off, 64);
  if (lane == 0) wsum[w] = psum;
  __syncthreads();
  if (t == 0) gpart[bid] = wsum[0] + wsum[1] + wsum[2] + wsum[3];
}

// Single-block tree reduction of all partials -> 3 outputs.
__global__ void finalize(const float* __restrict__ dpart, const float* __restrict__ ppart,
                         const float* __restrict__ gpart, float* __restrict__ out) {
  const int t = threadIdx.x;    // 256 threads
  float ds = 0.f, ps = 0.f;
  for (int i = t; i < 8192; i += 256) { ds += dpart[i]; ps += ppart[i]; }
  for (int i = t; i < 512; i += 256) ps += gpart[i];

#pragma unroll
  for (int off = 32; off > 0; off >>= 1) {
    ds += __shfl_down(ds, off, 64);
    ps += __shfl_down(ps, off, 64);
  }
  __shared__ float sd[4], sp[4];
  const int lane = t & 63, w = t >> 6;
  if (lane == 0) { sd[w] = ds; sp[w] = ps; }
  __syncthreads();
  if (t == 0) {
    float data = (sd[0] + sd[1] + sd[2] + sd[3]) * INV_COUNT;
    float phys = (sp[0] + sp[1] + sp[2] + sp[3]) * INV_COUNT;
    out[0] = data + 0.1f * phys;
    out[1] = data;
    out[2] = phys;
  }
}

extern "C" void kernel_launch(void* const* d_in, const int* in_sizes, int n_in,
                              void* d_out, int out_size, void* d_ws, size_t ws_size,
                              hipStream_t stream) {
  const float* u_pred = (const float*)d_in[0];
  const float* u_true = (const float*)d_in[1];
  float* out = (float*)d_out;

  char* ws = (char*)d_ws;
  float* dpart = (float*)ws;                                    // 8192 floats (32 KiB)
  float* ppart = (float*)(ws + 32768);                          // 8192 floats (32 KiB)
  float* gpart = (float*)(ws + 65536);                          // 512 floats (2 KiB)
  __hip_bfloat16* Mt = (__hip_bfloat16*)(ws + 131072);          // 1024*1024*2 = 2 MiB
  __hip_bfloat16* du = (__hip_bfloat16*)(ws + 131072 + 2097152);// 8192*1024*2 = 16 MiB

  prep<<<9216, 256, 0, stream>>>(u_pred, u_true, du, Mt, dpart, ppart);
  gemm<<<512, 256, 0, stream>>>(du, Mt, gpart);
  finalize<<<1, 256, 0, stream>>>(dpart, ppart, gpart, out);
}

// Round 8
// 47.240 us; speedup vs baseline: 1.2960x; 1.0586x over previous
//
#include <hip/hip_runtime.h>
#include <hip/hip_bf16.h>

// Problem constants: B=32, T=256, N=1024 -> R = 8192 rows, K = N-1 = 1023 (padded to 1024)
// alpha = 0.5, b[m] = sqrt(m+1)-sqrt(m) = 1/(sqrt(m+1)+sqrt(m)), coef = sqrt(1023)/Gamma(1.5)
#define COEF 36.090511f
#define INV_COUNT (1.0f / 8388608.0f)   // 1 / (32*256*1024)

typedef __attribute__((ext_vector_type(4))) float f32x4;
typedef __attribute__((ext_vector_type(2))) unsigned long long u64x2;

typedef const __attribute__((address_space(1))) unsigned int* gas_ptr;
typedef __attribute__((address_space(3))) unsigned int* las_ptr;

__device__ __forceinline__ void load_lds16(const void* g, void* l) {
  __builtin_amdgcn_global_load_lds((gas_ptr)g, (las_ptr)l, 16, 0, 0);
}

// manual OCP e4m3fn decode (bias 7): exact, no header/builtin dependency
__device__ __forceinline__ float fp8_dec(unsigned int v) {
  const unsigned e = (v >> 3) & 0xF, m = v & 7;
  const int mant = e ? (8 + (int)m) : (int)m;
  const int ee = e ? (int)e : 1;
  float f = (float)mant * __int_as_float((ee + 117) << 23);  // mant * 2^(ee-10)
  return (v & 0x80) ? -f : f;
}

// prep blocks 0..8191: du8 = fp8(u_pred diffs), col 1023 = 0 pad; per-row partials.
// blocks 8192..9215: Mt8[i][j] = fp8(b[i-j]) (transposed Toeplitz), one row each.
__global__ void prep(const float* __restrict__ up, const float* __restrict__ utr,
                     unsigned char* __restrict__ du8, unsigned char* __restrict__ Mt8,
                     float* __restrict__ dpart, float* __restrict__ ppart) {
  const int t = threadIdx.x;      // 256 threads
  if (blockIdx.x >= 8192) {
    const int i = blockIdx.x - 8192;    // Mt row 0..1023
    const int j0 = t * 4;
    float v[4];
#pragma unroll
    for (int e = 0; e < 4; e++) {
      int m = i - (j0 + e);
      v[e] = 0.f;
      if (m >= 0) { float fm_ = (float)m; v[e] = 1.0f / (sqrtf(fm_ + 1.f) + sqrtf(fm_)); }
    }
    int w_ = __builtin_amdgcn_cvt_pk_fp8_f32(v[0], v[1], 0, false);
    w_ = __builtin_amdgcn_cvt_pk_fp8_f32(v[2], v[3], w_, true);
    *(unsigned int*)(Mt8 + (size_t)i * 1024 + j0) = (unsigned int)w_;
    return;
  }

  const int r = blockIdx.x;       // 8192 rows
  const int j0 = t * 4;
  const float* rowp = up + (size_t)r * 1024;

  f32x4 a = *(const f32x4*)(rowp + j0);
  float a4 = (t < 255) ? rowp[j0 + 4] : 0.f;
  f32x4 b = *(const f32x4*)(utr + (size_t)r * 1024 + j0);

  float d0 = a[1] - a[0];
  float d1 = a[2] - a[1];
  float d2 = a[3] - a[2];
  float d3 = (t < 255) ? (a4 - a[3]) : 0.f;   // du[1023] = 0 pad

  int w_ = __builtin_amdgcn_cvt_pk_fp8_f32(d0, d1, 0, false);
  w_ = __builtin_amdgcn_cvt_pk_fp8_f32(d2, d3, w_, true);
  *(unsigned int*)(du8 + (size_t)r * 1024 + j0) = (unsigned int)w_;

  float e0 = a[0] - b[0], e1 = a[1] - b[1], e2 = a[2] - b[2], e3 = a[3] - b[3];
  float dsum = e0 * e0 + e1 * e1 + e2 * e2 + e3 * e3;

#pragma unroll
  for (int off = 32; off > 0; off >>= 1) dsum += __shfl_down(dsum, off, 64);
  __shared__ float ws4[4];
  const int lane = t & 63, w = t >> 6;
  if (lane == 0) ws4[w] = dsum;
  __syncthreads();
  if (t == 0) {
    dpart[r] = ws4[0] + ws4[1] + ws4[2] + ws4[3];
    ppart[r] = d0 * d0;   // physics residual at n=0: u_t = du[r,0], frac_lap[0] = 0
  }
}

// Y[r,i] = sum_j du[r,j] * b[i-j]; fused epilogue: resid = u_t - COEF*Y, accumulate resid^2.
// fp8 GEMM: 128x128 tile, BK=128 bytes (byte-layout identical to the bf16 BK=64 version),
// 4 waves, double-buffered LDS, XOR quad-swizzle, counted vmcnt(8), XCD+triangular map.
// K-slot relabel: lane g4 owns k-bytes [g4*32, g4*32+32) = quads 2g4,2g4+1; each 8-byte
// half is one MFMA window. A and B use the same relabel -> permutation cancels.
__launch_bounds__(256, 2)
__global__ void gemm(const unsigned char* __restrict__ du8,
                     const unsigned char* __restrict__ Mt8,
                     float* __restrict__ gpart) {
  __shared__ unsigned char sA[2][16384];   // [128 rows][128 k-bytes], quad-swizzled
  __shared__ unsigned char sB[2][16384];
  __shared__ float wsum[4];

  const int t = threadIdx.x;
  const int w = t >> 6;
  const int lane = t & 63;

  const int bid = blockIdx.x;      // 0..511
  const int xcd = bid & 7;
  const int local = bid >> 3;      // 0..63
  const int e = local & 1;
  const int j = local >> 1;        // 0..31
  const int h = (j < 16) ? (j & 7) : 7 - (j & 7);
  const int cb = e ? 7 - h : h;                 // pairs (2k,2k+1) and (k,k+32) both sum to 7
  const int rb = xcd * 8 + (((j >> 3) << 1) | e);   // bijective with cb per XCD
  const int row0 = rb * 128;
  const int col0 = cb * 128;
  const int nkb = cb + 1;          // K-blocks of 128 bytes (triangular skip)

  const f32x4 vzero = {0.f, 0.f, 0.f, 0.f};
  f32x4 acc[4][4];
#pragma unroll
  for (int i = 0; i < 4; i++)
#pragma unroll
    for (int jj = 0; jj < 4; jj++) acc[i][jj] = vzero;

  // staging: thread t covers (row = t>>3, phys quad = t&7); source quad = phys ^ (row&7)
  const int srow = t >> 3;                            // 0..31
  const int scol = ((t & 7) ^ (srow & 7)) * 16;       // pre-swizzled source byte col
  const unsigned char* gA0 = du8 + (size_t)(row0 + srow) * 1024 + scol;
  const unsigned char* gB0 = Mt8 + (size_t)(col0 + srow) * 1024 + scol;

  auto stage = [&](int buf, int kb) {
    const int kc = kb * 128;
#pragma unroll
    for (int l = 0; l < 4; l++)
      load_lds16(gA0 + (size_t)l * 32 * 1024 + kc, (void*)&sA[buf][l * 4096 + t * 16]);
#pragma unroll
    for (int l = 0; l < 4; l++)
      load_lds16(gB0 + (size_t)l * 32 * 1024 + kc, (void*)&sB[buf][l * 4096 + t * 16]);
  };

  const int wm = w >> 1, wn = w & 1;
  const int frow = lane & 15;
  const int g4 = lane >> 4;              // lane's k-owner group 0..3

  auto compute = [&](int buf) {
#pragma unroll
    for (int p = 0; p < 2; p++) {
      const int lq = g4 * 2 + p;               // logical quad
      const int ph = lq ^ (frow & 7);          // physical quad (swizzle)
      u64x2 aV[4], bV[4];
#pragma unroll
      for (int fm = 0; fm < 4; fm++)
        aV[fm] = *(const u64x2*)&sA[buf][(wm * 64 + fm * 16 + frow) * 128 + ph * 16];
#pragma unroll
      for (int fn = 0; fn < 4; fn++)
        bV[fn] = *(const u64x2*)&sB[buf][(wn * 64 + fn * 16 + frow) * 128 + ph * 16];
#pragma unroll
      for (int fm = 0; fm < 4; fm++)
#pragma unroll
        for (int fn = 0; fn < 4; fn++) {
          acc[fm][fn] = __builtin_amdgcn_mfma_f32_16x16x32_fp8_fp8(
              (long long)aV[fm].x, (long long)bV[fn].x, acc[fm][fn], 0, 0, 0);
          acc[fm][fn] = __builtin_amdgcn_mfma_f32_16x16x32_fp8_fp8(
              (long long)aV[fm].y, (long long)bV[fn].y, acc[fm][fn], 0, 0, 0);
        }
    }
  };

  stage(0, 0);
  for (int kb = 0; kb < nkb; kb++) {
    // BARRIER A: all waves done computing kb-1 -> buf (kb+1)&1 free to overwrite
    asm volatile("" ::: "memory");
    __builtin_amdgcn_s_barrier();
    asm volatile("" ::: "memory");
    if (kb + 1 < nkb) {
      stage((kb + 1) & 1, kb + 1);                    // 8 loads in flight across barrier
      asm volatile("s_waitcnt vmcnt(8)" ::: "memory"); // current tile's 8 complete
    } else {
      asm volatile("s_waitcnt vmcnt(0)" ::: "memory"); // last tile: drain
    }
    // BARRIER B: every wave's current-tile loads complete
    __builtin_amdgcn_s_barrier();
    asm volatile("" ::: "memory");
    compute(kb & 1);
  }

  // fused epilogue: C/D layout col = lane&15, row = (lane>>4)*4 + reg  [HW-verified]
  float psum = 0.f;
  const int rbase = row0 + wm * 64 + (lane >> 4) * 4;
  const int ibase = col0 + wn * 64 + frow;
#pragma unroll
  for (int fm = 0; fm < 4; fm++) {
#pragma unroll
    for (int fn = 0; fn < 4; fn++) {
      const int icol = ibase + fn * 16;        // du index i; output position n = i+1
      if (icol < 1023) {
#pragma unroll
        for (int reg = 0; reg < 4; reg++) {
          const int r = rbase + fm * 16 + reg;
          float frac = COEF * acc[fm][fn][reg];
          float dui = fp8_dec(du8[(size_t)r * 1024 + icol]);
          float ut;
          if (icol == 1022) {
            ut = dui;                           // n = N-1 edge: u_t = du[N-2]
          } else {
            float dui1 = fp8_dec(du8[(size_t)r * 1024 + icol + 1]);
            ut = 0.5f * (dui + dui1);           // central difference
          }
          float res = ut - frac;
          psum += res * res;
        }
      }
    }
  }

#pragma unroll
  for (int off = 32; off > 0; off >>= 1) psum += __shfl_down(psum, off, 64);
  if (lane == 0) wsum[w] = psum;
  __syncthreads();
  if (t == 0) gpart[bid] = wsum[0] + wsum[1] + wsum[2] + wsum[3];
}

// Single-block tree reduction of all partials -> 3 outputs.
__global__ void finalize(const float* __restrict__ dpart, const float* __restrict__ ppart,
                         const float* __restrict__ gpart, float* __restrict__ out) {
  const int t = threadIdx.x;    // 256 threads
  float ds = 0.f, ps = 0.f;
  for (int i = t; i < 8192; i += 256) { ds += dpart[i]; ps += ppart[i]; }
  for (int i = t; i < 512; i += 256) ps += gpart[i];

#pragma unroll
  for (int off = 32; off > 0; off >>= 1) {
    ds += __shfl_down(ds, off, 64);
    ps += __shfl_down(ps, off, 64);
  }
  __shared__ float sd[4], sp[4];
  const int lane = t & 63, w = t >> 6;
  if (lane == 0) { sd[w] = ds; sp[w] = ps; }
  __syncthreads();
  if (t == 0) {
    float data = (sd[0] + sd[1] + sd[2] + sd[3]) * INV_COUNT;
    float phys = (sp[0] + sp[1] + sp[2] + sp[3]) * INV_COUNT;
    out[0] = data + 0.1f * phys;
    out[1] = data;
    out[2] = phys;
  }
}

extern "C" void kernel_launch(void* const* d_in, const int* in_sizes, int n_in,
                              void* d_out, int out_size, void* d_ws, size_t ws_size,
                              hipStream_t stream) {
  const float* u_pred = (const float*)d_in[0];
  const float* u_true = (const float*)d_in[1];
  float* out = (float*)d_out;

  char* ws = (char*)d_ws;
  float* dpart = (float*)ws;                                    // 8192 floats (32 KiB)
  float* ppart = (float*)(ws + 32768);                          // 8192 floats (32 KiB)
  float* gpart = (float*)(ws + 65536);                          // 512 floats (2 KiB)
  unsigned char* Mt8 = (unsigned char*)(ws + 131072);           // 1024*1024 = 1 MiB
  unsigned char* du8 = (unsigned char*)(ws + 131072 + 1048576); // 8192*1024 = 8 MiB

  prep<<<9216, 256, 0, stream>>>(u_pred, u_true, du8, Mt8, dpart, ppart);
  gemm<<<512, 256, 0, stream>>>(du8, Mt8, gpart);
  finalize<<<1, 256, 0, stream>>>(dpart, ppart, gpart, out);
}